// Round 1
// baseline (152.886 us; speedup 1.0000x reference)
//
#include <hip/hip_runtime.h>
#include <hip/hip_bf16.h>

#define HIDDEN 128
#define N_NEI 32

// One wave (64 lanes) per node; 4 waves per block.
// score[n,k] = sigmoid( dot(neibour[n,k,:],Wn) + dot(sub_graph[n,:],Ws) + b ) + mask[n,k]
// out[n,:]   = softmax(score[n,:])
__global__ __launch_bounds__(256) void score_softmax_kernel(
    const float* __restrict__ neibour,      // [N, 32, 128]
    const float* __restrict__ sub_graph,    // [N, 128]
    const float* __restrict__ nei_pad_mask, // [N, 32]
    const float* __restrict__ W,            // [256] (Wn = W[0:128], Ws = W[128:256])
    const float* __restrict__ b,            // [1]
    float* __restrict__ out,                // [N, 32]
    int n_nodes)
{
    const int wave = threadIdx.x >> 6;      // 0..3
    const int lane = threadIdx.x & 63;
    const int node = blockIdx.x * 4 + wave;
    if (node >= n_nodes) return;

    __shared__ float score_lds[4][N_NEI];

    const int half = lane >> 5;             // 0 or 1
    const int l32  = lane & 31;

    // Wn fragment: lane holds Wn[l32*4 .. l32*4+3] (same in both halves). Cached in L1/L2.
    const float4 wn = *reinterpret_cast<const float4*>(W + l32 * 4);

    // ---- sn = dot(sub_graph[node], Ws) + b : all 64 lanes, 2 elems each ----
    const float2 sg = *reinterpret_cast<const float2*>(sub_graph + (size_t)node * HIDDEN + lane * 2);
    const float2 ws = *reinterpret_cast<const float2*>(W + HIDDEN + lane * 2);
    float sn = sg.x * ws.x + sg.y * ws.y;
    #pragma unroll
    for (int m = 1; m < 64; m <<= 1) sn += __shfl_xor(sn, m, 64);
    sn += b[0];

    // ---- 32 neighbor dots: each 32-lane half does one row per iteration ----
    const float* nb = neibour + (size_t)node * N_NEI * HIDDEN;
    #pragma unroll
    for (int kk = 0; kk < 16; ++kk) {
        const int row = kk * 2 + half;
        const float4 v = *reinterpret_cast<const float4*>(nb + row * HIDDEN + l32 * 4);
        float p = v.x * wn.x + v.y * wn.y + v.z * wn.z + v.w * wn.w;
        #pragma unroll
        for (int m = 1; m < 32; m <<= 1) p += __shfl_xor(p, m, 64);  // reduce within half
        if (l32 == 0) score_lds[wave][row] = p;
    }
    // within-wave LDS write->read: ordered by compiler-inserted lgkmcnt waits; no barrier needed
    // (each wave only touches its own score_lds[wave] slice)

    // ---- sigmoid + mask + softmax over the 32 neighbors ----
    float sc = score_lds[wave][l32] + sn;
    sc = 1.0f / (1.0f + expf(-sc));
    sc += nei_pad_mask[(size_t)node * N_NEI + l32];

    float mx = sc;
    #pragma unroll
    for (int m = 1; m < 32; m <<= 1) mx = fmaxf(mx, __shfl_xor(mx, m, 64));
    float e = expf(sc - mx);
    float ssum = e;
    #pragma unroll
    for (int m = 1; m < 32; m <<= 1) ssum += __shfl_xor(ssum, m, 64);

    if (half == 0) out[(size_t)node * N_NEI + l32] = e / ssum;
}

extern "C" void kernel_launch(void* const* d_in, const int* in_sizes, int n_in,
                              void* d_out, int out_size, void* d_ws, size_t ws_size,
                              hipStream_t stream) {
    // setup_inputs order: x, neibour, sub_graph, pmi, nei_pad_mask, W, b
    const float* neibour      = (const float*)d_in[1];
    const float* sub_graph    = (const float*)d_in[2];
    const float* nei_pad_mask = (const float*)d_in[4];
    const float* W            = (const float*)d_in[5];
    const float* b            = (const float*)d_in[6];
    float* out = (float*)d_out;

    const int n_nodes = in_sizes[4] / N_NEI;   // nei_pad_mask is [N, 32]
    const int blocks  = (n_nodes + 3) / 4;     // 4 nodes (waves) per block

    score_softmax_kernel<<<blocks, 256, 0, stream>>>(
        neibour, sub_graph, nei_pad_mask, W, b, out, n_nodes);
}

// Round 2
// 148.911 us; speedup vs baseline: 1.0267x; 1.0267x over previous
//
#include <hip/hip_runtime.h>
#include <hip/hip_bf16.h>

#define HIDDEN 128
#define N_NEI 32

// Butterfly multi-reduce merge: combines two 32-lane-spread partial vectors
// (rows A,B) into one, halving lanes-per-row. 1 shuffle + 2 selects + 1 add.
__device__ __forceinline__ float merge2(float a, float b, int m, int lane) {
    const bool hi = (lane & m) != 0;
    const float keep = hi ? b : a;
    const float send = hi ? a : b;
    return keep + __shfl_xor(send, m, 64);
}

// One wave (64 lanes) per node; 4 waves per block. No LDS.
__global__ __launch_bounds__(256) void score_softmax_kernel(
    const float* __restrict__ neibour,      // [N, 32, 128]
    const float* __restrict__ sub_graph,    // [N, 128]
    const float* __restrict__ nei_pad_mask, // [N, 32]
    const float* __restrict__ W,            // [256] (Wn = W[0:128], Ws = W[128:256])
    const float* __restrict__ b,            // [1]
    float* __restrict__ out,                // [N, 32]
    int n_nodes)
{
    const int wave = threadIdx.x >> 6;
    const int lane = threadIdx.x & 63;
    const int node = blockIdx.x * 4 + wave;
    if (node >= n_nodes) return;

    const int half = lane >> 5;             // 0 or 1
    const int l32  = lane & 31;

    // Wn fragment: lane holds Wn[l32*4 .. l32*4+3] (same in both halves).
    const float4 wn = *reinterpret_cast<const float4*>(W + l32 * 4);

    // ---- sn = dot(sub_graph[node], Ws) + b : all 64 lanes, 2 elems each ----
    const float2 sg = *reinterpret_cast<const float2*>(sub_graph + (size_t)node * HIDDEN + lane * 2);
    const float2 ws = *reinterpret_cast<const float2*>(W + HIDDEN + lane * 2);
    float sn = fmaf(sg.x, ws.x, sg.y * ws.y);
    #pragma unroll
    for (int m = 1; m < 64; m <<= 1) sn += __shfl_xor(sn, m, 64);
    sn += b[0];

    // ---- 16 partial dots per half; half h handles rows 2*kk + h ----
    const float* nb = neibour + (size_t)node * (N_NEI * HIDDEN);
    float p[16];
    #pragma unroll
    for (int kk = 0; kk < 16; ++kk) {
        const float4 v = *reinterpret_cast<const float4*>(nb + (2 * kk + half) * HIDDEN + l32 * 4);
        p[kk] = fmaf(v.x, wn.x, fmaf(v.y, wn.y, fmaf(v.z, wn.z, v.w * wn.w)));
    }

    // ---- merge tree: 15 single-shuffle merges + 1 final xor-1 ----
    // After this, lane holds the full dot for p-index pidx(lane) (see below),
    // duplicated on lane^1.
    float r[8];
    #pragma unroll
    for (int i = 0; i < 8; ++i) r[i] = merge2(p[2*i], p[2*i+1], 16, lane);
    float s4[4];
    #pragma unroll
    for (int i = 0; i < 4; ++i) s4[i] = merge2(r[2*i], r[2*i+1], 8, lane);
    float t2[2];
    #pragma unroll
    for (int i = 0; i < 2; ++i) t2[i] = merge2(s4[2*i], s4[2*i+1], 4, lane);
    float u = merge2(t2[0], t2[1], 2, lane);
    u += __shfl_xor(u, 1, 64);

    // lane -> row: p-index bits come from lane bits 4..1 (bit-reversed by tree)
    const int pidx = ((lane >> 4) & 1) | (((lane >> 3) & 1) << 1)
                   | (((lane >> 2) & 1) << 2) | (((lane >> 1) & 1) << 3);
    const int row = 2 * pidx + half;

    // ---- sigmoid + mask + softmax over the 32 rows (each held by 2 lanes) ----
    float sc = u + sn;
    sc = 1.0f / (1.0f + __expf(-sc));
    sc += nei_pad_mask[(size_t)node * N_NEI + row];

    float mx = sc;
    #pragma unroll
    for (int m = 1; m < 64; m <<= 1) mx = fmaxf(mx, __shfl_xor(mx, m, 64));
    float e = __expf(sc - mx);
    float ssum = e;                          // 64-lane sum counts each row twice
    #pragma unroll
    for (int m = 1; m < 64; m <<= 1) ssum += __shfl_xor(ssum, m, 64);

    if ((lane & 1) == 0)
        out[(size_t)node * N_NEI + row] = e * 2.0f / ssum;
}

extern "C" void kernel_launch(void* const* d_in, const int* in_sizes, int n_in,
                              void* d_out, int out_size, void* d_ws, size_t ws_size,
                              hipStream_t stream) {
    // setup_inputs order: x, neibour, sub_graph, pmi, nei_pad_mask, W, b
    const float* neibour      = (const float*)d_in[1];
    const float* sub_graph    = (const float*)d_in[2];
    const float* nei_pad_mask = (const float*)d_in[4];
    const float* W            = (const float*)d_in[5];
    const float* b            = (const float*)d_in[6];
    float* out = (float*)d_out;

    const int n_nodes = in_sizes[4] / N_NEI;   // nei_pad_mask is [N, 32]
    const int blocks  = (n_nodes + 3) / 4;     // 4 nodes (waves) per block

    score_softmax_kernel<<<blocks, 256, 0, stream>>>(
        neibour, sub_graph, nei_pad_mask, W, b, out, n_nodes);
}

// Round 3
// 140.219 us; speedup vs baseline: 1.0903x; 1.0620x over previous
//
#include <hip/hip_runtime.h>
#include <hip/hip_bf16.h>

#define HIDDEN 128
#define N_NEI 32

typedef float f32x4 __attribute__((ext_vector_type(4)));

// Butterfly multi-reduce merge: combines two 32-lane-spread partial vectors
// (rows A,B) into one, halving lanes-per-row. 1 shuffle + 2 selects + 1 add.
__device__ __forceinline__ float merge2(float a, float b, int m, int lane) {
    const bool hi = (lane & m) != 0;
    const float keep = hi ? b : a;
    const float send = hi ? a : b;
    return keep + __shfl_xor(send, m, 64);
}

// Persistent waves, one node per wave per iteration, next node's loads
// issued before the dependent shuffle/softmax tail (software pipeline).
__global__ __launch_bounds__(256) void score_softmax_kernel(
    const float* __restrict__ neibour,      // [N, 32, 128]
    const float* __restrict__ sub_graph,    // [N, 128]
    const float* __restrict__ nei_pad_mask, // [N, 32]
    const float* __restrict__ W,            // [256]
    const float* __restrict__ b,            // [1]
    float* __restrict__ out,                // [N, 32]
    int n_nodes)
{
    const int wave = threadIdx.x >> 6;
    const int lane = threadIdx.x & 63;
    const int half = lane >> 5;             // 0 or 1
    const int l32  = lane & 31;
    const int wgid = blockIdx.x * 4 + wave; // global wave id
    const int wstride = gridDim.x * 4;

    // lane -> row this lane will own after the merge tree (bit-reversed)
    const int pidx = ((lane >> 4) & 1) | (((lane >> 3) & 1) << 1)
                   | (((lane >> 2) & 1) << 2) | (((lane >> 1) & 1) << 3);
    const int row = 2 * pidx + half;

    // Loop-invariant weights
    const f32x4 wn = *reinterpret_cast<const f32x4*>(W + l32 * 4);
    const float2 ws = *reinterpret_cast<const float2*>(W + HIDDEN + lane * 2);
    const float bias = b[0];

    int node = wgid;
    if (node >= n_nodes) return;

    f32x4 v[16];
    float2 sgv;
    float maskv;

#define LOAD_NODE(nd) do {                                                    \
        const float* nb_ = neibour + (size_t)(nd) * (N_NEI * HIDDEN);         \
        _Pragma("unroll")                                                     \
        for (int kk = 0; kk < 16; ++kk)                                       \
            v[kk] = __builtin_nontemporal_load(                               \
                reinterpret_cast<const f32x4*>(nb_ + (2 * kk + half) * HIDDEN \
                                               + l32 * 4));                   \
        sgv = *reinterpret_cast<const float2*>(                               \
            sub_graph + (size_t)(nd) * HIDDEN + lane * 2);                    \
        maskv = nei_pad_mask[(size_t)(nd) * N_NEI + row];                     \
    } while (0)

    LOAD_NODE(node);   // prologue

    #pragma unroll 1
    while (node < n_nodes) {
        // ---- consume current registers into partials (waits on loads) ----
        float p[16];
        #pragma unroll
        for (int kk = 0; kk < 16; ++kk)
            p[kk] = fmaf(v[kk].x, wn.x, fmaf(v[kk].y, wn.y,
                     fmaf(v[kk].z, wn.z, v[kk].w * wn.w)));
        float sn = fmaf(sgv.x, ws.x, sgv.y * ws.y);
        const float mask_cur = maskv;

        // ---- issue next node's loads; tail below overlaps their flight ----
        const int next = node + wstride;
        if (next < n_nodes) LOAD_NODE(next);

        // ---- sub_graph dot: 64-lane butterfly ----
        #pragma unroll
        for (int m = 1; m < 64; m <<= 1) sn += __shfl_xor(sn, m, 64);
        sn += bias;

        // ---- merge tree: 15 single-shuffle merges + final xor-1 ----
        float r[8];
        #pragma unroll
        for (int i = 0; i < 8; ++i) r[i] = merge2(p[2*i], p[2*i+1], 16, lane);
        float s4[4];
        #pragma unroll
        for (int i = 0; i < 4; ++i) s4[i] = merge2(r[2*i], r[2*i+1], 8, lane);
        float t2[2];
        #pragma unroll
        for (int i = 0; i < 2; ++i) t2[i] = merge2(s4[2*i], s4[2*i+1], 4, lane);
        float u = merge2(t2[0], t2[1], 2, lane);
        u += __shfl_xor(u, 1, 64);

        // ---- sigmoid + mask + softmax ----
        // lanes l and l^1 hold the same row -> reduce over masks 2..32 only:
        // that set covers each of the 32 rows exactly once (no double count).
        float sc = u + sn;
        sc = 1.0f / (1.0f + __expf(-sc));
        sc += mask_cur;

        float mx = sc;
        #pragma unroll
        for (int m = 2; m < 64; m <<= 1) mx = fmaxf(mx, __shfl_xor(mx, m, 64));
        float e = __expf(sc - mx);
        float ssum = e;
        #pragma unroll
        for (int m = 2; m < 64; m <<= 1) ssum += __shfl_xor(ssum, m, 64);

        if ((lane & 1) == 0)
            __builtin_nontemporal_store(e / ssum, out + (size_t)node * N_NEI + row);

        node = next;
    }
#undef LOAD_NODE
}

extern "C" void kernel_launch(void* const* d_in, const int* in_sizes, int n_in,
                              void* d_out, int out_size, void* d_ws, size_t ws_size,
                              hipStream_t stream) {
    // setup_inputs order: x, neibour, sub_graph, pmi, nei_pad_mask, W, b
    const float* neibour      = (const float*)d_in[1];
    const float* sub_graph    = (const float*)d_in[2];
    const float* nei_pad_mask = (const float*)d_in[4];
    const float* W            = (const float*)d_in[5];
    const float* b            = (const float*)d_in[6];
    float* out = (float*)d_out;

    const int n_nodes = in_sizes[4] / N_NEI;     // nei_pad_mask is [N, 32]

    // Persistent grid: 4 blocks/CU (16 waves/CU at ~100 VGPR), grid-stride.
    int blocks = 1024;
    const int max_blocks = (n_nodes + 3) / 4;
    if (blocks > max_blocks) blocks = max_blocks;

    score_softmax_kernel<<<blocks, 256, 0, stream>>>(
        neibour, sub_graph, nei_pad_mask, W, b, out, n_nodes);
}